// Round 1
// baseline (1432.431 us; speedup 1.0000x reference)
//
#include <hip/hip_runtime.h>
#include <math.h>

#define N_NODES 50000
#define E_EDGES 800000
#define IN_DIM  256
#define D_DIM   96
#define OUT_DIM 128

// ---------- monotonic float<->uint key for atomicMax on floats ----------
__device__ __forceinline__ unsigned fkey(float f) {
    unsigned u = __float_as_uint(f);
    return (u & 0x80000000u) ? ~u : (u | 0x80000000u);
}
__device__ __forceinline__ float fkey_inv(unsigned k) {
    unsigned u = (k & 0x80000000u) ? (k & 0x7fffffffu) : ~k;
    return __uint_as_float(u);
}

// ---------- K1: feat = x @ W_fc  ([N,256] @ [256,96] -> [N,96]) ----------
__global__ __launch_bounds__(192)
void k_featmm(const float* __restrict__ x, const float* __restrict__ Wfc,
              float* __restrict__ feat) {
    __shared__ float xs[64][68];              // [k][n], pad 68 -> 272B rows (16B aligned)
    const int t    = threadIdx.x;
    const int j    = t % 96;                  // output column
    const int half = t / 96;                  // node sub-tile
    const int n0   = blockIdx.x * 64;
    const int bn   = half * 32;

    float acc[32];
#pragma unroll
    for (int i = 0; i < 32; ++i) acc[i] = 0.f;

    for (int k0 = 0; k0 < IN_DIM; k0 += 64) {
        __syncthreads();
        for (int idx = t; idx < 64 * 64; idx += 192) {
            int nl = idx >> 6, kk = idx & 63;
            int n = n0 + nl;
            xs[kk][nl] = (n < N_NODES) ? x[n * IN_DIM + k0 + kk] : 0.f;
        }
        __syncthreads();
#pragma unroll 4
        for (int kk = 0; kk < 64; ++kk) {
            float w = Wfc[(k0 + kk) * D_DIM + j];      // coalesced across lanes
            const float4* row = (const float4*)&xs[kk][bn];
#pragma unroll
            for (int q = 0; q < 8; ++q) {
                float4 v = row[q];                     // LDS broadcast
                acc[4*q+0] += w * v.x; acc[4*q+1] += w * v.y;
                acc[4*q+2] += w * v.z; acc[4*q+3] += w * v.w;
            }
        }
    }
#pragma unroll
    for (int i = 0; i < 32; ++i) {
        int n = n0 + bn + i;
        if (n < N_NODES) feat[n * D_DIM + j] = acc[i];
    }
}

// ---------- K2: el/er per node + init emax key / esum ----------
__global__ __launch_bounds__(256)
void k_node_attn(const float* __restrict__ feat,
                 const float* __restrict__ al, const float* __restrict__ ar,
                 float* __restrict__ el, float* __restrict__ er,
                 unsigned* __restrict__ emaxk, float* __restrict__ esum) {
    int n = blockIdx.x * blockDim.x + threadIdx.x;
    if (n >= N_NODES) return;
    const float4* f4 = (const float4*)(feat + n * D_DIM);
    float sl = 0.f, sr = 0.f;
#pragma unroll
    for (int q = 0; q < 24; ++q) {
        float4 v = f4[q];
        float4 a = ((const float4*)al)[q];
        float4 b = ((const float4*)ar)[q];
        sl += v.x*a.x + v.y*a.y + v.z*a.z + v.w*a.w;
        sr += v.x*b.x + v.y*b.y + v.z*b.z + v.w*b.w;
    }
    el[n] = sl; er[n] = sr;
    emaxk[n] = 0u;        // acts as -inf (all finite keys >= 0x00800000)
    esum[n]  = 0.f;
}

// ---------- K3a: e = leaky_relu(el[src]+er[dst]); segment max ----------
__global__ __launch_bounds__(256)
void k_edge_max(const int* __restrict__ src, const int* __restrict__ dst,
                const float* __restrict__ el, const float* __restrict__ er,
                float* __restrict__ ev, unsigned* __restrict__ emaxk) {
    int e = blockIdx.x * blockDim.x + threadIdx.x;
    if (e >= E_EDGES) return;
    float v = el[src[e]] + er[dst[e]];
    v = v > 0.f ? v : 0.2f * v;
    ev[e] = v;
    atomicMax(&emaxk[dst[e]], fkey(v));
}

// ---------- K3b: ex = exp(e - emax[dst]); segment sum ----------
__global__ __launch_bounds__(256)
void k_edge_exp(const int* __restrict__ dst, const unsigned* __restrict__ emaxk,
                float* __restrict__ ev, float* __restrict__ esum) {
    int e = blockIdx.x * blockDim.x + threadIdx.x;
    if (e >= E_EDGES) return;
    int d = dst[e];
    float x = expf(ev[e] - fkey_inv(emaxk[d]));
    ev[e] = x;
    atomicAdd(&esum[d], x);
}

// ---------- K3c: rst[dst] += ex * feat[src]  (unnormalized; /esum later) ----------
__global__ __launch_bounds__(256)
void k_edge_scatter(const int* __restrict__ src, const int* __restrict__ dst,
                    const float* __restrict__ ev, const float* __restrict__ feat,
                    float* __restrict__ rst) {
    int idx = blockIdx.x * blockDim.x + threadIdx.x;   // E*24 = 19.2M, fits int
    if (idx >= E_EDGES * 24) return;
    int e = idx / 24, q = idx % 24;
    float a = ev[e];
    float4 f = ((const float4*)(feat + src[e] * D_DIM))[q];
    float* r = rst + dst[e] * D_DIM + q * 4;
    atomicAdd(r + 0, a * f.x); atomicAdd(r + 1, a * f.y);
    atomicAdd(r + 2, a * f.z); atomicAdd(r + 3, a * f.w);
}

// ---------- small transpose for weight matrices ----------
__global__ __launch_bounds__(256)
void k_transpose(const float* __restrict__ in, float* __restrict__ out,
                 int rows, int cols) {
    int tid = blockIdx.x * blockDim.x + threadIdx.x;
    if (tid >= rows * cols) return;
    int r = tid / cols, c = tid % cols;
    out[c * rows + r] = in[r * cols + c];
}

// ---------- K4: xmid=tanh(rst/esum+bias); gates; LSTM cell; outputs ----------
__global__ __launch_bounds__(256)
void k_lstm(const float* __restrict__ rst, const float* __restrict__ esum,
            const float* __restrict__ bias,
            const float* __restrict__ WihT,   // [96][512]
            const float* __restrict__ WhhT,   // [128][512]
            const float* __restrict__ b_ih, const float* __restrict__ b_hh,
            const float* __restrict__ h0, const float* __restrict__ c0,
            float* __restrict__ out_h1a, float* __restrict__ out_h1b,
            float* __restrict__ out_c1) {
    __shared__ float xs[96][36];       // [k][n], 144B rows (16B aligned)
    __shared__ float hs[128][36];
    __shared__ float sfo[2][32][128];  // sigmoid(f), sigmoid(o)
    const int t  = threadIdx.x;
    const int n0 = blockIdx.x * 32;

    // phase 1: xmid tile (transposed into LDS)
    for (int idx = t; idx < 32 * 96; idx += 256) {
        int n = idx / 96, k = idx % 96;
        int gn = n0 + n;
        float v = 0.f;
        if (gn < N_NODES) {
            float s = esum[gn];
            float den = s > 0.f ? s : 1.f;
            v = tanhf(rst[gn * D_DIM + k] / den + bias[k]);
        }
        xs[k][n] = v;
    }
    // phase 2: h0 tile
    for (int idx = t; idx < 32 * 128; idx += 256) {
        int n = idx >> 7, k = idx & 127;
        int gn = n0 + n;
        hs[k][n] = (gn < N_NODES) ? h0[gn * OUT_DIM + k] : 0.f;
    }
    __syncthreads();

    // phase 3: gates for cols j0=t, j1=t+256, 32 nodes each
    const int j0 = t, j1 = t + 256;
    float acc0[32], acc1[32];
    const float i0 = b_ih[j0] + b_hh[j0];
    const float i1 = b_ih[j1] + b_hh[j1];
#pragma unroll
    for (int i = 0; i < 32; ++i) { acc0[i] = i0; acc1[i] = i1; }

#pragma unroll 4
    for (int k = 0; k < 96; ++k) {
        float w0 = WihT[k * 512 + j0];
        float w1 = WihT[k * 512 + j1];
        const float4* row = (const float4*)&xs[k][0];
#pragma unroll
        for (int q = 0; q < 8; ++q) {
            float4 v = row[q];
            acc0[4*q+0] += w0*v.x; acc0[4*q+1] += w0*v.y;
            acc0[4*q+2] += w0*v.z; acc0[4*q+3] += w0*v.w;
            acc1[4*q+0] += w1*v.x; acc1[4*q+1] += w1*v.y;
            acc1[4*q+2] += w1*v.z; acc1[4*q+3] += w1*v.w;
        }
    }
#pragma unroll 4
    for (int k = 0; k < 128; ++k) {
        float w0 = WhhT[k * 512 + j0];
        float w1 = WhhT[k * 512 + j1];
        const float4* row = (const float4*)&hs[k][0];
#pragma unroll
        for (int q = 0; q < 8; ++q) {
            float4 v = row[q];
            acc0[4*q+0] += w0*v.x; acc0[4*q+1] += w0*v.y;
            acc0[4*q+2] += w0*v.z; acc0[4*q+3] += w0*v.w;
            acc1[4*q+0] += w1*v.x; acc1[4*q+1] += w1*v.y;
            acc1[4*q+2] += w1*v.z; acc1[4*q+3] += w1*v.w;
        }
    }

    // phase 4: LSTM pointwise. t in [128,256): f (acc0), o (acc1). Exchange via LDS.
    if (t >= 128) {
        int c = t - 128;
#pragma unroll
        for (int i = 0; i < 32; ++i) {
            sfo[0][i][c] = 1.f / (1.f + expf(-acc0[i]));   // sigmoid(f)
            sfo[1][i][c] = 1.f / (1.f + expf(-acc1[i]));   // sigmoid(o)
        }
    }
    __syncthreads();
    if (t < 128) {
        int c = t;
        for (int i = 0; i < 32; ++i) {
            int gn = n0 + i;
            if (gn >= N_NODES) break;
            float ig = 1.f / (1.f + expf(-acc0[i]));       // sigmoid(i)
            float g  = tanhf(acc1[i]);                     // tanh(g)
            float c1 = sfo[0][i][c] * c0[gn * OUT_DIM + c] + ig * g;
            float h1 = sfo[1][i][c] * tanhf(c1);
            out_h1a[gn * OUT_DIM + c] = h1;
            out_h1b[gn * OUT_DIM + c] = h1;
            out_c1 [gn * OUT_DIM + c] = c1;
        }
    }
}

extern "C" void kernel_launch(void* const* d_in, const int* in_sizes, int n_in,
                              void* d_out, int out_size, void* d_ws, size_t ws_size,
                              hipStream_t stream) {
    const float* x      = (const float*)d_in[0];
    const float* W_fc   = (const float*)d_in[1];
    const float* attn_l = (const float*)d_in[2];
    const float* attn_r = (const float*)d_in[3];
    const float* bias   = (const float*)d_in[4];
    const float* W_ih   = (const float*)d_in[5];
    const float* W_hh   = (const float*)d_in[6];
    const float* b_ih   = (const float*)d_in[7];
    const float* b_hh   = (const float*)d_in[8];
    const float* h0     = (const float*)d_in[9];
    const float* c0     = (const float*)d_in[10];
    const int*   src    = (const int*)d_in[11];
    const int*   dst    = (const int*)d_in[12];
    float* out = (float*)d_out;

    float* ws = (float*)d_ws;
    float*    feat  = ws;                                   // N*96  = 4.8M floats
    float*    rst   = ws + 4800000;                         // N*96  = 4.8M
    float*    el    = ws + 9600000;                         // N
    float*    er    = el + N_NODES;                         // N
    unsigned* emaxk = (unsigned*)(er + N_NODES);            // N
    float*    esum  = (float*)(emaxk + N_NODES);            // N
    float*    ev    = esum + N_NODES;                       // E
    float*    WihT  = ev + E_EDGES;                         // 96*512
    float*    WhhT  = WihT + 96 * 512;                      // 128*512
    // total ~10.72M floats = 42.9 MB of d_ws

    hipMemsetAsync(rst, 0, (size_t)N_NODES * D_DIM * sizeof(float), stream);

    k_transpose<<<(512 * 96  + 255) / 256, 256, 0, stream>>>(W_ih, WihT, 512, 96);
    k_transpose<<<(512 * 128 + 255) / 256, 256, 0, stream>>>(W_hh, WhhT, 512, 128);

    k_featmm<<<(N_NODES + 63) / 64, 192, 0, stream>>>(x, W_fc, feat);
    k_node_attn<<<(N_NODES + 255) / 256, 256, 0, stream>>>(feat, attn_l, attn_r,
                                                           el, er, emaxk, esum);
    k_edge_max<<<(E_EDGES + 255) / 256, 256, 0, stream>>>(src, dst, el, er, ev, emaxk);
    k_edge_exp<<<(E_EDGES + 255) / 256, 256, 0, stream>>>(dst, emaxk, ev, esum);
    k_edge_scatter<<<(E_EDGES * 24 + 255) / 256, 256, 0, stream>>>(src, dst, ev, feat, rst);

    k_lstm<<<(N_NODES + 31) / 32, 256, 0, stream>>>(rst, esum, bias, WihT, WhhT,
                                                    b_ih, b_hh, h0, c0,
                                                    out, out + N_NODES * OUT_DIM,
                                                    out + 2 * N_NODES * OUT_DIM);
}

// Round 2
// 586.186 us; speedup vs baseline: 2.4436x; 2.4436x over previous
//
#include <hip/hip_runtime.h>
#include <math.h>

#define N_NODES 50000
#define E_EDGES 800000
#define IN_DIM  256
#define D_DIM   96
#define OUT_DIM 128

// ---------- K1: feat = x @ W_fc  ([N,256] @ [256,96] -> [N,96]) ----------
__global__ __launch_bounds__(192)
void k_featmm(const float* __restrict__ x, const float* __restrict__ Wfc,
              float* __restrict__ feat) {
    __shared__ float xs[64][68];              // [k][n], pad 68 -> 272B rows (16B aligned)
    const int t    = threadIdx.x;
    const int j    = t % 96;                  // output column
    const int half = t / 96;                  // node sub-tile
    const int n0   = blockIdx.x * 64;
    const int bn   = half * 32;

    float acc[32];
#pragma unroll
    for (int i = 0; i < 32; ++i) acc[i] = 0.f;

    for (int k0 = 0; k0 < IN_DIM; k0 += 64) {
        __syncthreads();
        for (int idx = t; idx < 64 * 64; idx += 192) {
            int nl = idx >> 6, kk = idx & 63;
            int n = n0 + nl;
            xs[kk][nl] = (n < N_NODES) ? x[n * IN_DIM + k0 + kk] : 0.f;
        }
        __syncthreads();
#pragma unroll 4
        for (int kk = 0; kk < 64; ++kk) {
            float w = Wfc[(k0 + kk) * D_DIM + j];      // coalesced across lanes
            const float4* row = (const float4*)&xs[kk][bn];
#pragma unroll
            for (int q = 0; q < 8; ++q) {
                float4 v = row[q];                     // LDS broadcast
                acc[4*q+0] += w * v.x; acc[4*q+1] += w * v.y;
                acc[4*q+2] += w * v.z; acc[4*q+3] += w * v.w;
            }
        }
    }
#pragma unroll
    for (int i = 0; i < 32; ++i) {
        int n = n0 + bn + i;
        if (n < N_NODES) feat[n * D_DIM + j] = acc[i];
    }
}

// ---------- K2: el/er per node ----------
__global__ __launch_bounds__(256)
void k_node_attn(const float* __restrict__ feat,
                 const float* __restrict__ al, const float* __restrict__ ar,
                 float* __restrict__ el, float* __restrict__ er) {
    int n = blockIdx.x * blockDim.x + threadIdx.x;
    if (n >= N_NODES) return;
    const float4* f4 = (const float4*)(feat + n * D_DIM);
    float sl = 0.f, sr = 0.f;
#pragma unroll
    for (int q = 0; q < 24; ++q) {
        float4 v = f4[q];
        float4 a = ((const float4*)al)[q];
        float4 b = ((const float4*)ar)[q];
        sl += v.x*a.x + v.y*a.y + v.z*a.z + v.w*a.w;
        sr += v.x*b.x + v.y*b.y + v.z*b.z + v.w*b.w;
    }
    el[n] = sl; er[n] = sr;
}

// ---------- K3a: histogram of dst ----------
__global__ __launch_bounds__(256)
void k_hist(const int* __restrict__ dst, int* __restrict__ cnt) {
    int e = blockIdx.x * blockDim.x + threadIdx.x;
    if (e >= E_EDGES) return;
    atomicAdd(&cnt[dst[e]], 1);
}

// ---------- K3b: exclusive scan (single block, 1024 threads) ----------
__global__ __launch_bounds__(1024)
void k_scan(const int* __restrict__ cnt, int* __restrict__ offs,
            int* __restrict__ cursor) {
    __shared__ int part[1024];
    const int t = threadIdx.x;
    const int chunk = (N_NODES + 1023) / 1024;   // 49
    const int b = t * chunk;
    int s = 0;
    for (int i = 0; i < chunk; ++i) { int n = b + i; if (n < N_NODES) s += cnt[n]; }
    part[t] = s;
    __syncthreads();
    for (int d = 1; d < 1024; d <<= 1) {
        int v = (t >= d) ? part[t - d] : 0;
        __syncthreads();
        part[t] += v;
        __syncthreads();
    }
    int run = (t == 0) ? 0 : part[t - 1];
    for (int i = 0; i < chunk; ++i) {
        int n = b + i;
        if (n < N_NODES) { offs[n] = run; cursor[n] = run; run += cnt[n]; }
    }
    if (t == 1023) offs[N_NODES] = run;          // == E
}

// ---------- K3c: bucket src-ids by dst ----------
__global__ __launch_bounds__(256)
void k_bucket(const int* __restrict__ src, const int* __restrict__ dst,
              int* __restrict__ cursor, int* __restrict__ ebuf_src) {
    int e = blockIdx.x * blockDim.x + threadIdx.x;
    if (e >= E_EDGES) return;
    int pos = atomicAdd(&cursor[dst[e]], 1);
    ebuf_src[pos] = src[e];
}

// ---------- K3d: per-node softmax-gather -> xmid = tanh(rst/esum + bias) ----------
__global__ __launch_bounds__(256)
void k_gather(const int* __restrict__ offs, const int* __restrict__ ebuf_src,
              const float* __restrict__ el, const float* __restrict__ er,
              const float* __restrict__ feat, const float* __restrict__ bias,
              float* __restrict__ xmid) {
    const int n    = (blockIdx.x * 256 + threadIdx.x) >> 5;   // one 32-lane group per node
    const int lane = threadIdx.x & 31;
    if (n >= N_NODES) return;
    const int o0 = offs[n], o1 = offs[n + 1];
    const int deg = o1 - o0;
    const float ern = er[n];

    // max over incoming edges
    float vmax = -INFINITY;
    for (int i = lane; i < deg; i += 32) {
        int s = ebuf_src[o0 + i];
        float v = el[s] + ern; v = v > 0.f ? v : 0.2f * v;
        vmax = fmaxf(vmax, v);
    }
#pragma unroll
    for (int d = 16; d; d >>= 1) vmax = fmaxf(vmax, __shfl_xor(vmax, d, 32));

    // sum of exp
    float ssum = 0.f;
    for (int i = lane; i < deg; i += 32) {
        int s = ebuf_src[o0 + i];
        float v = el[s] + ern; v = v > 0.f ? v : 0.2f * v;
        ssum += __expf(v - vmax);
    }
#pragma unroll
    for (int d = 16; d; d >>= 1) ssum += __shfl_xor(ssum, d, 32);

    const float inv = 1.f / (ssum > 0.f ? ssum : 1.f);

    // weighted gather of feat[src] (serial over edges, lanes over D)
    float a0 = 0.f, a1 = 0.f, a2 = 0.f;
    for (int i = 0; i < deg; ++i) {
        int s = ebuf_src[o0 + i];                         // broadcast load
        float v = el[s] + ern; v = v > 0.f ? v : 0.2f * v;
        float w = __expf(v - vmax);
        const float* fr = feat + s * D_DIM;
        a0 += w * fr[lane];
        a1 += w * fr[lane + 32];
        a2 += w * fr[lane + 64];
    }
    xmid[n * D_DIM + lane]      = tanhf(a0 * inv + bias[lane]);
    xmid[n * D_DIM + lane + 32] = tanhf(a1 * inv + bias[lane + 32]);
    xmid[n * D_DIM + lane + 64] = tanhf(a2 * inv + bias[lane + 64]);
}

// ---------- small transpose for weight matrices ----------
__global__ __launch_bounds__(256)
void k_transpose(const float* __restrict__ in, float* __restrict__ out,
                 int rows, int cols) {
    int tid = blockIdx.x * blockDim.x + threadIdx.x;
    if (tid >= rows * cols) return;
    int r = tid / cols, c = tid % cols;
    out[c * rows + r] = in[r * cols + c];
}

// ---------- K4: gates = xmid@WihT + h0@WhhT + b; LSTM cell; outputs ----------
__global__ __launch_bounds__(256)
void k_lstm(const float* __restrict__ xmid,
            const float* __restrict__ WihT,   // [96][512]
            const float* __restrict__ WhhT,   // [128][512]
            const float* __restrict__ b_ih, const float* __restrict__ b_hh,
            const float* __restrict__ h0, const float* __restrict__ c0,
            float* __restrict__ out_h1a, float* __restrict__ out_h1b,
            float* __restrict__ out_c1) {
    __shared__ float xs[96][36];       // [k][n], 144B rows (16B aligned)
    __shared__ float hs[128][36];
    __shared__ float sfo[2][32][128];  // sigmoid(f), sigmoid(o)
    const int t  = threadIdx.x;
    const int n0 = blockIdx.x * 32;

    // phase 1: xmid tile (transposed into LDS)
    for (int idx = t; idx < 32 * 96; idx += 256) {
        int n = idx / 96, k = idx % 96;
        int gn = n0 + n;
        xs[k][n] = (gn < N_NODES) ? xmid[gn * D_DIM + k] : 0.f;
    }
    // phase 2: h0 tile
    for (int idx = t; idx < 32 * 128; idx += 256) {
        int n = idx >> 7, k = idx & 127;
        int gn = n0 + n;
        hs[k][n] = (gn < N_NODES) ? h0[gn * OUT_DIM + k] : 0.f;
    }
    __syncthreads();

    // phase 3: gates for cols j0=t, j1=t+256, 32 nodes each
    const int j0 = t, j1 = t + 256;
    float acc0[32], acc1[32];
    const float i0 = b_ih[j0] + b_hh[j0];
    const float i1 = b_ih[j1] + b_hh[j1];
#pragma unroll
    for (int i = 0; i < 32; ++i) { acc0[i] = i0; acc1[i] = i1; }

#pragma unroll 4
    for (int k = 0; k < 96; ++k) {
        float w0 = WihT[k * 512 + j0];
        float w1 = WihT[k * 512 + j1];
        const float4* row = (const float4*)&xs[k][0];
#pragma unroll
        for (int q = 0; q < 8; ++q) {
            float4 v = row[q];
            acc0[4*q+0] += w0*v.x; acc0[4*q+1] += w0*v.y;
            acc0[4*q+2] += w0*v.z; acc0[4*q+3] += w0*v.w;
            acc1[4*q+0] += w1*v.x; acc1[4*q+1] += w1*v.y;
            acc1[4*q+2] += w1*v.z; acc1[4*q+3] += w1*v.w;
        }
    }
#pragma unroll 4
    for (int k = 0; k < 128; ++k) {
        float w0 = WhhT[k * 512 + j0];
        float w1 = WhhT[k * 512 + j1];
        const float4* row = (const float4*)&hs[k][0];
#pragma unroll
        for (int q = 0; q < 8; ++q) {
            float4 v = row[q];
            acc0[4*q+0] += w0*v.x; acc0[4*q+1] += w0*v.y;
            acc0[4*q+2] += w0*v.z; acc0[4*q+3] += w0*v.w;
            acc1[4*q+0] += w1*v.x; acc1[4*q+1] += w1*v.y;
            acc1[4*q+2] += w1*v.z; acc1[4*q+3] += w1*v.w;
        }
    }

    // phase 4: LSTM pointwise. t in [128,256): f (acc0), o (acc1). Exchange via LDS.
    if (t >= 128) {
        int c = t - 128;
#pragma unroll
        for (int i = 0; i < 32; ++i) {
            sfo[0][i][c] = 1.f / (1.f + expf(-acc0[i]));   // sigmoid(f)
            sfo[1][i][c] = 1.f / (1.f + expf(-acc1[i]));   // sigmoid(o)
        }
    }
    __syncthreads();
    if (t < 128) {
        int c = t;
        for (int i = 0; i < 32; ++i) {
            int gn = n0 + i;
            if (gn >= N_NODES) break;
            float ig = 1.f / (1.f + expf(-acc0[i]));       // sigmoid(i)
            float g  = tanhf(acc1[i]);                     // tanh(g)
            float c1 = sfo[0][i][c] * c0[gn * OUT_DIM + c] + ig * g;
            float h1 = sfo[1][i][c] * tanhf(c1);
            out_h1a[gn * OUT_DIM + c] = h1;
            out_h1b[gn * OUT_DIM + c] = h1;
            out_c1 [gn * OUT_DIM + c] = c1;
        }
    }
}

extern "C" void kernel_launch(void* const* d_in, const int* in_sizes, int n_in,
                              void* d_out, int out_size, void* d_ws, size_t ws_size,
                              hipStream_t stream) {
    const float* x      = (const float*)d_in[0];
    const float* W_fc   = (const float*)d_in[1];
    const float* attn_l = (const float*)d_in[2];
    const float* attn_r = (const float*)d_in[3];
    const float* bias   = (const float*)d_in[4];
    const float* W_ih   = (const float*)d_in[5];
    const float* W_hh   = (const float*)d_in[6];
    const float* b_ih   = (const float*)d_in[7];
    const float* b_hh   = (const float*)d_in[8];
    const float* h0     = (const float*)d_in[9];
    const float* c0     = (const float*)d_in[10];
    const int*   src    = (const int*)d_in[11];
    const int*   dst    = (const int*)d_in[12];
    float* out = (float*)d_out;

    float* ws = (float*)d_ws;
    float* feat  = ws;                                  // N*96 = 4.8M floats
    float* xmid  = ws + 4800000;                        // N*96 = 4.8M
    float* el    = ws + 9600000;                        // N
    float* er    = el + N_NODES;                        // N
    int*   cnt      = (int*)(er + N_NODES);             // N
    int*   offs     = cnt + N_NODES;                    // N+1
    int*   cursor   = offs + N_NODES + 1;               // N
    int*   ebuf_src = cursor + N_NODES;                 // E
    float* WihT  = (float*)(ebuf_src + E_EDGES);        // 96*512
    float* WhhT  = WihT + 96 * 512;                     // 128*512
    // total ~10.8M floats ≈ 43.4 MB of d_ws

    hipMemsetAsync(cnt, 0, (size_t)N_NODES * sizeof(int), stream);

    k_transpose<<<(512 * 96  + 255) / 256, 256, 0, stream>>>(W_ih, WihT, 512, 96);
    k_transpose<<<(512 * 128 + 255) / 256, 256, 0, stream>>>(W_hh, WhhT, 512, 128);

    k_featmm<<<(N_NODES + 63) / 64, 192, 0, stream>>>(x, W_fc, feat);
    k_node_attn<<<(N_NODES + 255) / 256, 256, 0, stream>>>(feat, attn_l, attn_r, el, er);

    k_hist  <<<(E_EDGES + 255) / 256, 256, 0, stream>>>(dst, cnt);
    k_scan  <<<1, 1024, 0, stream>>>(cnt, offs, cursor);
    k_bucket<<<(E_EDGES + 255) / 256, 256, 0, stream>>>(src, dst, cursor, ebuf_src);
    k_gather<<<(N_NODES * 32 + 255) / 256, 256, 0, stream>>>(offs, ebuf_src, el, er,
                                                             feat, bias, xmid);

    k_lstm<<<(N_NODES + 31) / 32, 256, 0, stream>>>(xmid, WihT, WhhT,
                                                    b_ih, b_hh, h0, c0,
                                                    out, out + N_NODES * OUT_DIM,
                                                    out + 2 * N_NODES * OUT_DIM);
}

// Round 3
// 418.455 us; speedup vs baseline: 3.4231x; 1.4008x over previous
//
#include <hip/hip_runtime.h>
#include <math.h>

#define N_NODES 50000
#define E_EDGES 800000
#define IN_DIM  256
#define D_DIM   96
#define OUT_DIM 128
#define ZK      224          // 96 + 128
#define ZROWS   50016        // 1563 * 32

typedef __attribute__((ext_vector_type(8))) short short8;
typedef __attribute__((ext_vector_type(4))) float f32x4;

__device__ __forceinline__ unsigned short f2bf(float f) {
    unsigned u = __float_as_uint(f);
    unsigned r = u + 0x7fffu + ((u >> 16) & 1u);
    return (unsigned short)(r >> 16);
}
__device__ __forceinline__ float bf2f(unsigned short u) {
    return __uint_as_float(((unsigned)u) << 16);
}

// ---------- K1: feat = x @ W_fc  ([N,256]@[256,96] -> bf16 [N,96]) ----------
__global__ __launch_bounds__(192)
void k_featmm(const float* __restrict__ x, const float* __restrict__ Wfc,
              unsigned short* __restrict__ feat) {
    __shared__ float xs[64][68];
    const int t    = threadIdx.x;
    const int j    = t % 96;
    const int half = t / 96;
    const int n0   = blockIdx.x * 64;
    const int bn   = half * 32;

    float acc[32];
#pragma unroll
    for (int i = 0; i < 32; ++i) acc[i] = 0.f;

    for (int k0 = 0; k0 < IN_DIM; k0 += 64) {
        __syncthreads();
        for (int idx = t; idx < 64 * 64; idx += 192) {
            int nl = idx >> 6, kk = idx & 63;
            int n = n0 + nl;
            xs[kk][nl] = (n < N_NODES) ? x[n * IN_DIM + k0 + kk] : 0.f;
        }
        __syncthreads();
#pragma unroll 4
        for (int kk = 0; kk < 64; ++kk) {
            float w = Wfc[(k0 + kk) * D_DIM + j];
            const float4* row = (const float4*)&xs[kk][bn];
#pragma unroll
            for (int q = 0; q < 8; ++q) {
                float4 v = row[q];
                acc[4*q+0] += w * v.x; acc[4*q+1] += w * v.y;
                acc[4*q+2] += w * v.z; acc[4*q+3] += w * v.w;
            }
        }
    }
#pragma unroll
    for (int i = 0; i < 32; ++i) {
        int n = n0 + bn + i;
        if (n < N_NODES) feat[n * D_DIM + j] = f2bf(acc[i]);
    }
}

// ---------- K2: el/er per node (bf16 feat) ----------
__global__ __launch_bounds__(256)
void k_node_attn(const unsigned short* __restrict__ feat,
                 const float* __restrict__ al, const float* __restrict__ ar,
                 float* __restrict__ el, float* __restrict__ er) {
    int n = blockIdx.x * blockDim.x + threadIdx.x;
    if (n >= N_NODES) return;
    const uint4* f4 = (const uint4*)(feat + n * D_DIM);   // 12 × 8 bf16
    float sl = 0.f, sr = 0.f;
#pragma unroll
    for (int q = 0; q < 12; ++q) {
        uint4 v = f4[q];
        unsigned uu[4] = {v.x, v.y, v.z, v.w};
#pragma unroll
        for (int p = 0; p < 4; ++p) {
            float f0 = bf2f((unsigned short)(uu[p] & 0xffffu));
            float f1 = bf2f((unsigned short)(uu[p] >> 16));
            int k = q * 8 + p * 2;
            sl += f0 * al[k] + f1 * al[k + 1];
            sr += f0 * ar[k] + f1 * ar[k + 1];
        }
    }
    el[n] = sl; er[n] = sr;
}

// ---------- K3a: histogram of dst ----------
__global__ __launch_bounds__(256)
void k_hist(const int* __restrict__ dst, int* __restrict__ cnt) {
    int e = blockIdx.x * blockDim.x + threadIdx.x;
    if (e >= E_EDGES) return;
    atomicAdd(&cnt[dst[e]], 1);
}

// ---------- K3b: exclusive scan (single block) ----------
__global__ __launch_bounds__(1024)
void k_scan(const int* __restrict__ cnt, int* __restrict__ offs,
            int* __restrict__ cursor) {
    __shared__ int part[1024];
    const int t = threadIdx.x;
    const int chunk = (N_NODES + 1023) / 1024;
    const int b = t * chunk;
    int s = 0;
    for (int i = 0; i < chunk; ++i) { int n = b + i; if (n < N_NODES) s += cnt[n]; }
    part[t] = s;
    __syncthreads();
    for (int d = 1; d < 1024; d <<= 1) {
        int v = (t >= d) ? part[t - d] : 0;
        __syncthreads();
        part[t] += v;
        __syncthreads();
    }
    int run = (t == 0) ? 0 : part[t - 1];
    for (int i = 0; i < chunk; ++i) {
        int n = b + i;
        if (n < N_NODES) { offs[n] = run; cursor[n] = run; run += cnt[n]; }
    }
    if (t == 1023) offs[N_NODES] = run;
}

// ---------- K3c: bucket src-ids by dst ----------
__global__ __launch_bounds__(256)
void k_bucket(const int* __restrict__ src, const int* __restrict__ dst,
              int* __restrict__ cursor, int* __restrict__ ebuf_src) {
    int e = blockIdx.x * blockDim.x + threadIdx.x;
    if (e >= E_EDGES) return;
    int pos = atomicAdd(&cursor[dst[e]], 1);
    ebuf_src[pos] = src[e];
}

// ---------- K3d: softmax-gather -> xmid (bf16) into Zb cols [0,96) ----------
__global__ __launch_bounds__(256)
void k_gather(const int* __restrict__ offs, const int* __restrict__ ebuf_src,
              const float* __restrict__ el, const float* __restrict__ er,
              const unsigned short* __restrict__ feat, const float* __restrict__ bias,
              unsigned short* __restrict__ Zb) {
    const int n    = (blockIdx.x * 256 + threadIdx.x) >> 5;
    const int lane = threadIdx.x & 31;
    if (n >= N_NODES) return;
    const int o0 = offs[n], o1 = offs[n + 1];
    const int deg = o1 - o0;
    const float ern = er[n];

    float vmax = -INFINITY;
    for (int i = lane; i < deg; i += 32) {
        int s = ebuf_src[o0 + i];
        float v = el[s] + ern; v = v > 0.f ? v : 0.2f * v;
        vmax = fmaxf(vmax, v);
    }
#pragma unroll
    for (int d = 16; d; d >>= 1) vmax = fmaxf(vmax, __shfl_xor(vmax, d, 32));

    float ssum = 0.f;
    for (int i = lane; i < deg; i += 32) {
        int s = ebuf_src[o0 + i];
        float v = el[s] + ern; v = v > 0.f ? v : 0.2f * v;
        ssum += __expf(v - vmax);
    }
#pragma unroll
    for (int d = 16; d; d >>= 1) ssum += __shfl_xor(ssum, d, 32);

    const float inv = 1.f / (ssum > 0.f ? ssum : 1.f);

    float a0 = 0.f, a1 = 0.f, a2 = 0.f;
    for (int i = 0; i < deg; ++i) {
        int s = ebuf_src[o0 + i];
        float v = el[s] + ern; v = v > 0.f ? v : 0.2f * v;
        float w = __expf(v - vmax);
        const unsigned short* fr = feat + s * D_DIM;
        a0 += w * bf2f(fr[lane]);
        a1 += w * bf2f(fr[lane + 32]);
        a2 += w * bf2f(fr[lane + 64]);
    }
    unsigned short* zr = Zb + (size_t)n * ZK;
    zr[lane]      = f2bf(tanhf(a0 * inv + bias[lane]));
    zr[lane + 32] = f2bf(tanhf(a1 * inv + bias[lane + 32]));
    zr[lane + 64] = f2bf(tanhf(a2 * inv + bias[lane + 64]));
}

// ---------- prep: h0 -> Zb cols [96,224), zero tail rows ----------
__global__ __launch_bounds__(256)
void k_prep_h0(const float* __restrict__ h0, unsigned short* __restrict__ Zb) {
    int tid = blockIdx.x * 256 + threadIdx.x;
    if (tid >= ZROWS * OUT_DIM) return;
    int n = tid >> 7, k = tid & 127;
    unsigned short* zr = Zb + (size_t)n * ZK;
    if (n < N_NODES) {
        zr[96 + k] = f2bf(h0[n * OUT_DIM + k]);
    } else {
        zr[96 + k] = 0;
        if (k < 96) zr[k] = 0;
    }
}

// ---------- prep: W -> fragment-major packed bf16 + bsum ----------
// Wb_frag[((cf*7+ks)*64+l)*8+j] = W[k][col], k=ks*32+(l>>4)*8+j, col=cf*16+(l&15)
__global__ __launch_bounds__(256)
void k_prep_w(const float* __restrict__ W_ih, const float* __restrict__ W_hh,
              const float* __restrict__ b_ih, const float* __restrict__ b_hh,
              unsigned short* __restrict__ Wb_frag, float* __restrict__ bsum) {
    int tid = blockIdx.x * 256 + threadIdx.x;
    if (tid < 512) bsum[tid] = b_ih[tid] + b_hh[tid];
    if (tid >= 32 * 7 * 64 * 8) return;
    int j = tid & 7;
    int rest = tid >> 3;
    int l = rest & 63;
    int rest2 = rest >> 6;
    int ks = rest2 % 7;
    int cf = rest2 / 7;
    int k   = ks * 32 + (l >> 4) * 8 + j;
    int col = cf * 16 + (l & 15);
    float v = (k < 96) ? W_ih[col * 96 + k] : W_hh[col * 128 + (k - 96)];
    Wb_frag[tid] = f2bf(v);
}

// ---------- K4: MFMA gates GEMM + LSTM pointwise (no LDS) ----------
// Block: 4 waves, 32 rows. Wave w: cols wc0=w*32 + {0,16}, gate stride 128.
__global__ __launch_bounds__(256)
void k_lstm_mfma(const unsigned short* __restrict__ Zb,
                 const unsigned short* __restrict__ Wb_frag,
                 const float* __restrict__ bsum,
                 const float* __restrict__ cin0,
                 float* __restrict__ out_h1a, float* __restrict__ out_h1b,
                 float* __restrict__ out_c1) {
    const int t     = threadIdx.x;
    const int lane  = t & 63;
    const int w     = t >> 6;
    const int wc0   = w * 32;
    const int n0    = blockIdx.x * 32;
    const int rfrag = lane & 15;        // row within fragment / col within C
    const int khalf = lane >> 4;        // 0..3

    f32x4 acc[2][2][4];
#pragma unroll
    for (int m = 0; m < 2; ++m)
#pragma unroll
        for (int cc = 0; cc < 2; ++cc)
#pragma unroll
            for (int g = 0; g < 4; ++g)
                acc[m][cc][g] = (f32x4){0.f, 0.f, 0.f, 0.f};

    const unsigned short* A0 = Zb + (size_t)(n0 + rfrag) * ZK + khalf * 8;
    const unsigned short* A1 = Zb + (size_t)(n0 + 16 + rfrag) * ZK + khalf * 8;

#pragma unroll
    for (int ks = 0; ks < 7; ++ks) {
        short8 a0 = *(const short8*)(A0 + ks * 32);
        short8 a1 = *(const short8*)(A1 + ks * 32);
#pragma unroll
        for (int g = 0; g < 4; ++g) {
#pragma unroll
            for (int cc = 0; cc < 2; ++cc) {
                int cf = w * 2 + cc + 8 * g;
                short8 b = *(const short8*)(Wb_frag + (size_t)((cf * 7 + ks) * 64 + lane) * 8);
                acc[0][cc][g] = __builtin_amdgcn_mfma_f32_16x16x32_bf16(a0, b, acc[0][cc][g], 0, 0, 0);
                acc[1][cc][g] = __builtin_amdgcn_mfma_f32_16x16x32_bf16(a1, b, acc[1][cc][g], 0, 0, 0);
            }
        }
    }

    // epilogue: per-lane LSTM pointwise (i,f,g,o all in same lane/reg)
#pragma unroll
    for (int m = 0; m < 2; ++m) {
#pragma unroll
        for (int cc = 0; cc < 2; ++cc) {
            const int col = wc0 + cc * 16 + rfrag;     // c in [0,128)
            const float bi = bsum[col];
            const float bf = bsum[col + 128];
            const float bg = bsum[col + 256];
            const float bo = bsum[col + 384];
#pragma unroll
            for (int reg = 0; reg < 4; ++reg) {
                const int r = n0 + m * 16 + khalf * 4 + reg;
                if (r < N_NODES) {
                    float iv = acc[m][cc][0][reg] + bi;
                    float fv = acc[m][cc][1][reg] + bf;
                    float gv = acc[m][cc][2][reg] + bg;
                    float ov = acc[m][cc][3][reg] + bo;
                    float si = 1.f / (1.f + __expf(-iv));
                    float sf = 1.f / (1.f + __expf(-fv));
                    float so = 1.f / (1.f + __expf(-ov));
                    float c1 = sf * cin0[r * OUT_DIM + col] + si * tanhf(gv);
                    float h1 = so * tanhf(c1);
                    out_h1a[r * OUT_DIM + col] = h1;
                    out_h1b[r * OUT_DIM + col] = h1;
                    out_c1 [r * OUT_DIM + col] = c1;
                }
            }
        }
    }
}

extern "C" void kernel_launch(void* const* d_in, const int* in_sizes, int n_in,
                              void* d_out, int out_size, void* d_ws, size_t ws_size,
                              hipStream_t stream) {
    const float* x      = (const float*)d_in[0];
    const float* W_fc   = (const float*)d_in[1];
    const float* attn_l = (const float*)d_in[2];
    const float* attn_r = (const float*)d_in[3];
    const float* bias   = (const float*)d_in[4];
    const float* W_ih   = (const float*)d_in[5];
    const float* W_hh   = (const float*)d_in[6];
    const float* b_ih   = (const float*)d_in[7];
    const float* b_hh   = (const float*)d_in[8];
    const float* h0     = (const float*)d_in[9];
    const float* c0     = (const float*)d_in[10];
    const int*   src    = (const int*)d_in[11];
    const int*   dst    = (const int*)d_in[12];
    float* out = (float*)d_out;

    char* base = (char*)d_ws;
    unsigned short* feat    = (unsigned short*)(base);               // 9,600,000 B
    unsigned short* Zb      = (unsigned short*)(base + 9600000);     // 22,407,168 B
    float*          el      = (float*)(base + 32007168);             // 200,000
    float*          er      = (float*)(base + 32207168);             // 200,000
    int*            cnt     = (int*)(base + 32407168);               // 200,000
    int*            offs    = (int*)(base + 32607168);               // 200,004
    int*            cursor  = (int*)(base + 32807172);               // 200,000
    int*            ebuf    = (int*)(base + 33007172);               // 3,200,000
    unsigned short* Wb_frag = (unsigned short*)(base + 36207184);    // 229,376
    float*          bsum    = (float*)(base + 36436560);             // 2,048

    hipMemsetAsync(cnt, 0, (size_t)N_NODES * sizeof(int), stream);

    k_prep_w <<<(32 * 7 * 64 * 8 + 255) / 256, 256, 0, stream>>>(W_ih, W_hh, b_ih, b_hh,
                                                                 Wb_frag, bsum);
    k_prep_h0<<<(ZROWS * OUT_DIM + 255) / 256, 256, 0, stream>>>(h0, Zb);

    k_featmm<<<(N_NODES + 63) / 64, 192, 0, stream>>>(x, W_fc, feat);
    k_node_attn<<<(N_NODES + 255) / 256, 256, 0, stream>>>(feat, attn_l, attn_r, el, er);

    k_hist  <<<(E_EDGES + 255) / 256, 256, 0, stream>>>(dst, cnt);
    k_scan  <<<1, 1024, 0, stream>>>(cnt, offs, cursor);
    k_bucket<<<(E_EDGES + 255) / 256, 256, 0, stream>>>(src, dst, cursor, ebuf);
    k_gather<<<(N_NODES * 32 + 255) / 256, 256, 0, stream>>>(offs, ebuf, el, er,
                                                             feat, bias, Zb);

    k_lstm_mfma<<<(N_NODES + 31) / 32, 256, 0, stream>>>(Zb, Wb_frag, bsum, c0,
                                                         out, out + N_NODES * OUT_DIM,
                                                         out + 2 * N_NODES * OUT_DIM);
}

// Round 4
// 321.752 us; speedup vs baseline: 4.4520x; 1.3006x over previous
//
#include <hip/hip_runtime.h>
#include <math.h>

#define N_NODES 50000
#define E_EDGES 800000
#define IN_DIM  256
#define D_DIM   96
#define OUT_DIM 128
#define ZK      224          // 96 + 128
#define ZROWS   50016        // 1563 * 32

typedef __attribute__((ext_vector_type(8))) short short8;
typedef __attribute__((ext_vector_type(4))) float f32x4;

__device__ __forceinline__ unsigned short f2bf(float f) {
    unsigned u = __float_as_uint(f);
    unsigned r = u + 0x7fffu + ((u >> 16) & 1u);
    return (unsigned short)(r >> 16);
}
__device__ __forceinline__ float bf2f(unsigned short u) {
    return __uint_as_float(((unsigned)u) << 16);
}

// ---------- K1: feat = x @ W_fc  ([N,256]@[256,96] -> bf16 [N,96]) ----------
__global__ __launch_bounds__(192)
void k_featmm(const float* __restrict__ x, const float* __restrict__ Wfc,
              unsigned short* __restrict__ feat) {
    __shared__ float xs[64][68];
    const int t    = threadIdx.x;
    const int j    = t % 96;
    const int half = t / 96;
    const int n0   = blockIdx.x * 64;
    const int bn   = half * 32;

    float acc[32];
#pragma unroll
    for (int i = 0; i < 32; ++i) acc[i] = 0.f;

    for (int k0 = 0; k0 < IN_DIM; k0 += 64) {
        __syncthreads();
        for (int idx = t; idx < 64 * 64; idx += 192) {
            int nl = idx >> 6, kk = idx & 63;
            int n = n0 + nl;
            xs[kk][nl] = (n < N_NODES) ? x[n * IN_DIM + k0 + kk] : 0.f;
        }
        __syncthreads();
#pragma unroll 4
        for (int kk = 0; kk < 64; ++kk) {
            float w = Wfc[(k0 + kk) * D_DIM + j];
            const float4* row = (const float4*)&xs[kk][bn];
#pragma unroll
            for (int q = 0; q < 8; ++q) {
                float4 v = row[q];
                acc[4*q+0] += w * v.x; acc[4*q+1] += w * v.y;
                acc[4*q+2] += w * v.z; acc[4*q+3] += w * v.w;
            }
        }
    }
#pragma unroll
    for (int i = 0; i < 32; ++i) {
        int n = n0 + bn + i;
        if (n < N_NODES) feat[n * D_DIM + j] = f2bf(acc[i]);
    }
}

// ---------- K2: el/er per node (bf16 feat) ----------
__global__ __launch_bounds__(256)
void k_node_attn(const unsigned short* __restrict__ feat,
                 const float* __restrict__ al, const float* __restrict__ ar,
                 float* __restrict__ el, float* __restrict__ er) {
    int n = blockIdx.x * blockDim.x + threadIdx.x;
    if (n >= N_NODES) return;
    const uint4* f4 = (const uint4*)(feat + n * D_DIM);   // 12 × 8 bf16
    float sl = 0.f, sr = 0.f;
#pragma unroll
    for (int q = 0; q < 12; ++q) {
        uint4 v = f4[q];
        unsigned uu[4] = {v.x, v.y, v.z, v.w};
#pragma unroll
        for (int p = 0; p < 4; ++p) {
            float f0 = bf2f((unsigned short)(uu[p] & 0xffffu));
            float f1 = bf2f((unsigned short)(uu[p] >> 16));
            int k = q * 8 + p * 2;
            sl += f0 * al[k] + f1 * al[k + 1];
            sr += f0 * ar[k] + f1 * ar[k + 1];
        }
    }
    el[n] = sl; er[n] = sr;
}

// ---------- K3a: histogram of dst ----------
__global__ __launch_bounds__(256)
void k_hist(const int* __restrict__ dst, int* __restrict__ cnt) {
    int e = blockIdx.x * blockDim.x + threadIdx.x;
    if (e >= E_EDGES) return;
    atomicAdd(&cnt[dst[e]], 1);
}

// ---------- K3b: wave-parallel range allocator (order-free "scan") ----------
__global__ __launch_bounds__(256)
void k_alloc(const int* __restrict__ cnt, int* __restrict__ start,
             int* __restrict__ cursor, int* __restrict__ total) {
    const int n    = blockIdx.x * 256 + threadIdx.x;
    const int lane = threadIdx.x & 63;
    int c = (n < N_NODES) ? cnt[n] : 0;
    int incl = c;
#pragma unroll
    for (int d = 1; d < 64; d <<= 1) {
        int v = __shfl_up(incl, d, 64);
        if (lane >= d) incl += v;
    }
    int wsum = __shfl(incl, 63, 64);
    int base = 0;
    if (lane == 63) base = atomicAdd(total, wsum);
    base = __shfl(base, 63, 64);
    if (n < N_NODES) {
        int s = base + incl - c;
        start[n] = s;
        cursor[n] = s;
    }
}

// ---------- K3c: bucket src-ids by dst ----------
__global__ __launch_bounds__(256)
void k_bucket(const int* __restrict__ src, const int* __restrict__ dst,
              int* __restrict__ cursor, int* __restrict__ ebuf_src) {
    int e = blockIdx.x * blockDim.x + threadIdx.x;
    if (e >= E_EDGES) return;
    int pos = atomicAdd(&cursor[dst[e]], 1);
    ebuf_src[pos] = src[e];
}

// ---------- K3d: softmax-gather -> xmid (bf16) into Zb cols [0,96) ----------
__global__ __launch_bounds__(256)
void k_gather(const int* __restrict__ start, const int* __restrict__ cnt,
              const int* __restrict__ ebuf_src,
              const float* __restrict__ el, const float* __restrict__ er,
              const unsigned short* __restrict__ feat, const float* __restrict__ bias,
              unsigned short* __restrict__ Zb) {
    const int n    = (blockIdx.x * 256 + threadIdx.x) >> 5;
    const int lane = threadIdx.x & 31;
    if (n >= N_NODES) return;
    const int o0 = start[n];
    const int deg = cnt[n];
    const float ern = er[n];

    float vmax = -INFINITY;
    for (int i = lane; i < deg; i += 32) {
        int s = ebuf_src[o0 + i];
        float v = el[s] + ern; v = v > 0.f ? v : 0.2f * v;
        vmax = fmaxf(vmax, v);
    }
#pragma unroll
    for (int d = 16; d; d >>= 1) vmax = fmaxf(vmax, __shfl_xor(vmax, d, 32));

    float ssum = 0.f;
    for (int i = lane; i < deg; i += 32) {
        int s = ebuf_src[o0 + i];
        float v = el[s] + ern; v = v > 0.f ? v : 0.2f * v;
        ssum += __expf(v - vmax);
    }
#pragma unroll
    for (int d = 16; d; d >>= 1) ssum += __shfl_xor(ssum, d, 32);

    const float inv = 1.f / (ssum > 0.f ? ssum : 1.f);

    float a0 = 0.f, a1 = 0.f, a2 = 0.f;
    for (int i = 0; i < deg; ++i) {
        int s = ebuf_src[o0 + i];
        float v = el[s] + ern; v = v > 0.f ? v : 0.2f * v;
        float w = __expf(v - vmax);
        const unsigned short* fr = feat + s * D_DIM;
        a0 += w * bf2f(fr[lane]);
        a1 += w * bf2f(fr[lane + 32]);
        a2 += w * bf2f(fr[lane + 64]);
    }
    unsigned short* zr = Zb + (size_t)n * ZK;
    zr[lane]      = f2bf(tanhf(a0 * inv + bias[lane]));
    zr[lane + 32] = f2bf(tanhf(a1 * inv + bias[lane + 32]));
    zr[lane + 64] = f2bf(tanhf(a2 * inv + bias[lane + 64]));
}

// ---------- prep: h0 -> Zb cols [96,224), zero tail rows ----------
__global__ __launch_bounds__(256)
void k_prep_h0(const float* __restrict__ h0, unsigned short* __restrict__ Zb) {
    int tid = blockIdx.x * 256 + threadIdx.x;
    if (tid >= ZROWS * OUT_DIM) return;
    int n = tid >> 7, k = tid & 127;
    unsigned short* zr = Zb + (size_t)n * ZK;
    if (n < N_NODES) {
        zr[96 + k] = f2bf(h0[n * OUT_DIM + k]);
    } else {
        zr[96 + k] = 0;
        if (k < 96) zr[k] = 0;
    }
}

// ---------- prep: W -> fragment-major packed bf16 + bsum ----------
// Wb_frag[((cf*7+ks)*64+l)*8+j] = W[k][col], k=ks*32+(l>>4)*8+j, col=cf*16+(l&15)
__global__ __launch_bounds__(256)
void k_prep_w(const float* __restrict__ W_ih, const float* __restrict__ W_hh,
              const float* __restrict__ b_ih, const float* __restrict__ b_hh,
              unsigned short* __restrict__ Wb_frag, float* __restrict__ bsum) {
    int tid = blockIdx.x * 256 + threadIdx.x;
    if (tid < 512) bsum[tid] = b_ih[tid] + b_hh[tid];
    if (tid >= 32 * 7 * 64 * 8) return;
    int j = tid & 7;
    int rest = tid >> 3;
    int l = rest & 63;
    int rest2 = rest >> 6;
    int ks = rest2 % 7;
    int cf = rest2 / 7;
    int k   = ks * 32 + (l >> 4) * 8 + j;
    int col = cf * 16 + (l & 15);
    float v = (k < 96) ? W_ih[col * 96 + k] : W_hh[col * 128 + (k - 96)];
    Wb_frag[tid] = f2bf(v);
}

// ---------- K4: MFMA gates GEMM + LSTM pointwise (no LDS) ----------
// Block: 4 waves, 32 rows. Wave w: cols wc0=w*32 + {0,16}, gate stride 128.
__global__ __launch_bounds__(256)
void k_lstm_mfma(const unsigned short* __restrict__ Zb,
                 const unsigned short* __restrict__ Wb_frag,
                 const float* __restrict__ bsum,
                 const float* __restrict__ cin0,
                 float* __restrict__ out_h1a, float* __restrict__ out_h1b,
                 float* __restrict__ out_c1) {
    const int t     = threadIdx.x;
    const int lane  = t & 63;
    const int w     = t >> 6;
    const int wc0   = w * 32;
    const int n0    = blockIdx.x * 32;
    const int rfrag = lane & 15;        // row within fragment / col within C
    const int khalf = lane >> 4;        // 0..3

    f32x4 acc[2][2][4];
#pragma unroll
    for (int m = 0; m < 2; ++m)
#pragma unroll
        for (int cc = 0; cc < 2; ++cc)
#pragma unroll
            for (int g = 0; g < 4; ++g)
                acc[m][cc][g] = (f32x4){0.f, 0.f, 0.f, 0.f};

    const unsigned short* A0 = Zb + (size_t)(n0 + rfrag) * ZK + khalf * 8;
    const unsigned short* A1 = Zb + (size_t)(n0 + 16 + rfrag) * ZK + khalf * 8;

#pragma unroll
    for (int ks = 0; ks < 7; ++ks) {
        short8 a0 = *(const short8*)(A0 + ks * 32);
        short8 a1 = *(const short8*)(A1 + ks * 32);
#pragma unroll
        for (int g = 0; g < 4; ++g) {
#pragma unroll
            for (int cc = 0; cc < 2; ++cc) {
                int cf = w * 2 + cc + 8 * g;
                short8 b = *(const short8*)(Wb_frag + (size_t)((cf * 7 + ks) * 64 + lane) * 8);
                acc[0][cc][g] = __builtin_amdgcn_mfma_f32_16x16x32_bf16(a0, b, acc[0][cc][g], 0, 0, 0);
                acc[1][cc][g] = __builtin_amdgcn_mfma_f32_16x16x32_bf16(a1, b, acc[1][cc][g], 0, 0, 0);
            }
        }
    }

    // epilogue: per-lane LSTM pointwise (i,f,g,o all in same lane/reg)
#pragma unroll
    for (int m = 0; m < 2; ++m) {
#pragma unroll
        for (int cc = 0; cc < 2; ++cc) {
            const int col = wc0 + cc * 16 + rfrag;     // c in [0,128)
            const float bi = bsum[col];
            const float bf = bsum[col + 128];
            const float bg = bsum[col + 256];
            const float bo = bsum[col + 384];
#pragma unroll
            for (int reg = 0; reg < 4; ++reg) {
                const int r = n0 + m * 16 + khalf * 4 + reg;
                if (r < N_NODES) {
                    float iv = acc[m][cc][0][reg] + bi;
                    float fv = acc[m][cc][1][reg] + bf;
                    float gv = acc[m][cc][2][reg] + bg;
                    float ov = acc[m][cc][3][reg] + bo;
                    float si = 1.f / (1.f + __expf(-iv));
                    float sf = 1.f / (1.f + __expf(-fv));
                    float so = 1.f / (1.f + __expf(-ov));
                    float c1 = sf * cin0[r * OUT_DIM + col] + si * tanhf(gv);
                    float h1 = so * tanhf(c1);
                    out_h1a[r * OUT_DIM + col] = h1;
                    out_h1b[r * OUT_DIM + col] = h1;
                    out_c1 [r * OUT_DIM + col] = c1;
                }
            }
        }
    }
}

extern "C" void kernel_launch(void* const* d_in, const int* in_sizes, int n_in,
                              void* d_out, int out_size, void* d_ws, size_t ws_size,
                              hipStream_t stream) {
    const float* x      = (const float*)d_in[0];
    const float* W_fc   = (const float*)d_in[1];
    const float* attn_l = (const float*)d_in[2];
    const float* attn_r = (const float*)d_in[3];
    const float* bias   = (const float*)d_in[4];
    const float* W_ih   = (const float*)d_in[5];
    const float* W_hh   = (const float*)d_in[6];
    const float* b_ih   = (const float*)d_in[7];
    const float* b_hh   = (const float*)d_in[8];
    const float* h0     = (const float*)d_in[9];
    const float* c0     = (const float*)d_in[10];
    const int*   src    = (const int*)d_in[11];
    const int*   dst    = (const int*)d_in[12];
    float* out = (float*)d_out;

    char* base = (char*)d_ws;
    unsigned short* feat    = (unsigned short*)(base);               // 9,600,000 B
    unsigned short* Zb      = (unsigned short*)(base + 9600000);     // 22,407,168 B
    float*          el      = (float*)(base + 32007168);             // 200,000
    float*          er      = (float*)(base + 32207168);             // 200,000
    int*            cnt     = (int*)(base + 32407168);               // 200,000
    int*            total   = (int*)(base + 32607168);               // 4 (+pad)
    int*            startv  = (int*)(base + 32607172);               // 200,000
    int*            cursor  = (int*)(base + 32807172);               // 200,000
    int*            ebuf    = (int*)(base + 33007172);               // 3,200,000
    unsigned short* Wb_frag = (unsigned short*)(base + 36207184);    // 229,376
    float*          bsum    = (float*)(base + 36436560);             // 2,048

    // zero cnt + total in one memset (they are contiguous)
    hipMemsetAsync(cnt, 0, (size_t)N_NODES * sizeof(int) + sizeof(int), stream);

    k_prep_w <<<(32 * 7 * 64 * 8 + 255) / 256, 256, 0, stream>>>(W_ih, W_hh, b_ih, b_hh,
                                                                 Wb_frag, bsum);
    k_prep_h0<<<(ZROWS * OUT_DIM + 255) / 256, 256, 0, stream>>>(h0, Zb);

    k_featmm<<<(N_NODES + 63) / 64, 192, 0, stream>>>(x, W_fc, feat);
    k_node_attn<<<(N_NODES + 255) / 256, 256, 0, stream>>>(feat, attn_l, attn_r, el, er);

    k_hist  <<<(E_EDGES + 255) / 256, 256, 0, stream>>>(dst, cnt);
    k_alloc <<<(N_NODES + 255) / 256, 256, 0, stream>>>(cnt, startv, cursor, total);
    k_bucket<<<(E_EDGES + 255) / 256, 256, 0, stream>>>(src, dst, cursor, ebuf);
    k_gather<<<(N_NODES * 32 + 255) / 256, 256, 0, stream>>>(startv, cnt, ebuf, el, er,
                                                             feat, bias, Zb);

    k_lstm_mfma<<<(N_NODES + 31) / 32, 256, 0, stream>>>(Zb, Wb_frag, bsum, c0,
                                                         out, out + N_NODES * OUT_DIM,
                                                         out + 2 * N_NODES * OUT_DIM);
}